// Round 4
// baseline (3278.841 us; speedup 1.0000x reference)
//
#include <hip/hip_runtime.h>
#include <cstdint>
#include <cstddef>

#define BATCH   4096
#define INDIM   1024
#define DICT    16384
#define TOTK    (32 * 4096)
#define NFEAT   ((size_t)BATCH * DICT)   // 67108864
#define NBINS   8192
#define CAND_CAP (1u << 18)

// ---------------- ws layout (byte offsets) ----------------
// [0, 32768)        hist: 8192 x u32
// [32768, 33024)    scal: 64 x u32 : 0=bin, 1=count_above, 2=cand_cnt,
//                                    3=thr_bits, 4=kept_count, 12..13=loss(double)
// [65536, +1MiB)    cand: CAND_CAP x u32
// [16MiB, +64MiB)   W_dec transposed [DICT][INDIM]
#define SCAL_OFF 32768
#define CAND_OFF 65536
#define WT_OFF   (16ull << 20)

// ======== encode: relu((x - b_dec) @ W_enc^T + b_enc) ========
// Replicates OpenBLAS sgemm rounding: per C element, fused-FMA sequential
// over k ascending, K split into panels (384, 320, 320) combined as
// ((P1 + P2) + P3) with one rounded f32 add per panel commit.
#define BM 64
#define BN 64
#define BK 32
__global__ __launch_bounds__(256) void encode_gemm(
    const float* __restrict__ x, const float* __restrict__ W,
    const float* __restrict__ b_enc, const float* __restrict__ b_dec,
    float* __restrict__ feat)
{
    __shared__ __align__(16) float As[BK][BM];
    __shared__ __align__(16) float Ws[BK][BN];
    const int tid = threadIdx.x;
    const int n0 = blockIdx.x * BN;   // dict dim
    const int m0 = blockIdx.y * BM;   // batch dim
    const int tm = tid >> 4, tn = tid & 15;
    const int sk = (tid & 7) * 4;     // k offset for staging
    const int sm = tid >> 3;          // row 0..31 for staging

    float tot[4][4];

    const int kb[4] = {0, 384, 704, 1024};   // OpenBLAS K-panel boundaries

    for (int p = 0; p < 3; ++p) {
        float acc[4][4] = {};
        for (int k0 = kb[p]; k0 < kb[p + 1]; k0 += BK) {
            const float4 bd = *reinterpret_cast<const float4*>(&b_dec[k0 + sk]);
#pragma unroll
            for (int r = 0; r < 2; ++r) {
                const int m = sm + r * 32;
                float4 v = *reinterpret_cast<const float4*>(&x[(size_t)(m0 + m) * INDIM + k0 + sk]);
                As[sk + 0][m] = v.x - bd.x;
                As[sk + 1][m] = v.y - bd.y;
                As[sk + 2][m] = v.z - bd.z;
                As[sk + 3][m] = v.w - bd.w;
                float4 w = *reinterpret_cast<const float4*>(&W[(size_t)(n0 + m) * INDIM + k0 + sk]);
                Ws[sk + 0][m] = w.x;
                Ws[sk + 1][m] = w.y;
                Ws[sk + 2][m] = w.z;
                Ws[sk + 3][m] = w.w;
            }
            __syncthreads();
#pragma unroll
            for (int kk = 0; kk < BK; ++kk) {
                const float4 av = *reinterpret_cast<const float4*>(&As[kk][tm * 4]);
                const float4 wv = *reinterpret_cast<const float4*>(&Ws[kk][tn * 4]);
                const float a[4] = {av.x, av.y, av.z, av.w};
                const float b[4] = {wv.x, wv.y, wv.z, wv.w};
#pragma unroll
                for (int i = 0; i < 4; ++i)
#pragma unroll
                    for (int j = 0; j < 4; ++j)
                        acc[i][j] = fmaf(a[i], b[j], acc[i][j]);
            }
            __syncthreads();
        }
        // panel commit: tot = ((P1 + P2) + P3), one rounded f32 add each
#pragma unroll
        for (int i = 0; i < 4; ++i)
#pragma unroll
            for (int j = 0; j < 4; ++j)
                tot[i][j] = (p == 0) ? acc[i][j] : (tot[i][j] + acc[i][j]);
    }

    const float4 be = *reinterpret_cast<const float4*>(&b_enc[n0 + tn * 4]);
    const float bea[4] = {be.x, be.y, be.z, be.w};
#pragma unroll
    for (int i = 0; i < 4; ++i) {
        const int row = m0 + tm * 4 + i;
        float4 out;
        out.x = fmaxf(tot[i][0] + bea[0], 0.0f);
        out.y = fmaxf(tot[i][1] + bea[1], 0.0f);
        out.z = fmaxf(tot[i][2] + bea[2], 0.0f);
        out.w = fmaxf(tot[i][3] + bea[3], 0.0f);
        *reinterpret_cast<float4*>(&feat[(size_t)row * DICT + n0 + tn * 4]) = out;
    }
}

// ================= histogram on top-14 bits of positive floats =================
__global__ __launch_bounds__(256) void hist_kernel(const float* __restrict__ feat,
                                                   unsigned* __restrict__ hist)
{
    __shared__ unsigned h[NBINS];
    for (int i = threadIdx.x; i < NBINS; i += blockDim.x) h[i] = 0;
    __syncthreads();
    const size_t stride = (size_t)gridDim.x * blockDim.x * 4;
    size_t base = ((size_t)blockIdx.x * blockDim.x + threadIdx.x) * 4;
    for (size_t i = base; i < NFEAT; i += stride) {
        const float4 v = *reinterpret_cast<const float4*>(&feat[i]);
        if (v.x > 0.f) atomicAdd(&h[__float_as_uint(v.x) >> 18], 1u);
        if (v.y > 0.f) atomicAdd(&h[__float_as_uint(v.y) >> 18], 1u);
        if (v.z > 0.f) atomicAdd(&h[__float_as_uint(v.z) >> 18], 1u);
        if (v.w > 0.f) atomicAdd(&h[__float_as_uint(v.w) >> 18], 1u);
    }
    __syncthreads();
    for (int i = threadIdx.x; i < NBINS; i += blockDim.x)
        if (h[i]) atomicAdd(&hist[i], h[i]);
}

// ================= find bin containing the k-th largest =================
__global__ __launch_bounds__(256) void findbin_kernel(const unsigned* __restrict__ hist,
                                                      unsigned* __restrict__ scal)
{
    __shared__ unsigned tsum[256];
    __shared__ unsigned suffix[256];
    const int t = threadIdx.x;
    unsigned loc[32];
    unsigned s = 0;
#pragma unroll
    for (int i = 0; i < 32; ++i) { loc[i] = hist[t * 32 + i]; s += loc[i]; }
    tsum[t] = s;
    __syncthreads();
    if (t == 0) {
        unsigned run = 0;
        for (int i = 255; i >= 0; --i) { suffix[i] = run; run += tsum[i]; }
    }
    __syncthreads();
    unsigned cum = suffix[t];  // count in all bins above this thread's chunk
    for (int i = 31; i >= 0; --i) {
        const unsigned nb = cum + loc[i];
        if (cum < TOTK && nb >= TOTK) {
            scal[0] = (unsigned)(t * 32 + i);
            scal[1] = cum;
        }
        cum = nb;
    }
}

// ============ collect candidate bit patterns in the crossing bin ============
__global__ __launch_bounds__(256) void collect_kernel(const float* __restrict__ feat,
                                                      unsigned* __restrict__ scal,
                                                      unsigned* __restrict__ cand)
{
    const unsigned b = scal[0];
    const size_t stride = (size_t)gridDim.x * blockDim.x;
    for (size_t i = (size_t)blockIdx.x * blockDim.x + threadIdx.x; i < NFEAT; i += stride) {
        const float v = feat[i];
        if (v > 0.f) {
            const unsigned u = __float_as_uint(v);
            if ((u >> 18) == b) {
                const unsigned idx = atomicAdd(&scal[2], 1u);
                if (idx < CAND_CAP) cand[idx] = u;
            }
        }
    }
}

// ====== exact f32 k-th largest via binary search on bit patterns ======
__global__ __launch_bounds__(256) void select_kernel(const unsigned* __restrict__ cand,
                                                     unsigned* __restrict__ scal)
{
    __shared__ unsigned cnt[256];
    const unsigned b = scal[0];
    const unsigned above = scal[1];
    const unsigned C = min(scal[2], CAND_CAP);
    const unsigned j = TOTK - above;  // 1-indexed rank within bin
    unsigned lo = b << 18;
    unsigned hi = ((b + 1) << 18) - 1;
    while (lo < hi) {
        const unsigned mid = lo + (hi - lo + 1) / 2;
        unsigned c = 0;
        for (unsigned i = threadIdx.x; i < C; i += 256) c += (cand[i] >= mid) ? 1u : 0u;
        cnt[threadIdx.x] = c;
        __syncthreads();
        for (int s = 128; s; s >>= 1) {
            if (threadIdx.x < s) cnt[threadIdx.x] += cnt[threadIdx.x + s];
            __syncthreads();
        }
        const unsigned tot = cnt[0];
        __syncthreads();
        if (tot >= j) lo = mid; else hi = mid - 1;
    }
    if (threadIdx.x == 0) scal[3] = lo;  // exact f32 rank-TOTK bit pattern
}

// ================= mask below threshold, count kept (for l0) =================
__global__ __launch_bounds__(256) void mask_kernel(float* __restrict__ feat,
                                                   unsigned* __restrict__ scal)
{
    __shared__ unsigned red[256];
    const float thr = __uint_as_float(scal[3]);
    unsigned kept = 0;
    const size_t stride = (size_t)gridDim.x * blockDim.x * 4;
    size_t base = ((size_t)blockIdx.x * blockDim.x + threadIdx.x) * 4;
    for (size_t i = base; i < NFEAT; i += stride) {
        float4 v = *reinterpret_cast<float4*>(&feat[i]);
        bool any = false;
        if (v.x >= thr) kept++; else { if (v.x != 0.f) { v.x = 0.f; any = true; } }
        if (v.y >= thr) kept++; else { if (v.y != 0.f) { v.y = 0.f; any = true; } }
        if (v.z >= thr) kept++; else { if (v.z != 0.f) { v.z = 0.f; any = true; } }
        if (v.w >= thr) kept++; else { if (v.w != 0.f) { v.w = 0.f; any = true; } }
        if (any) *reinterpret_cast<float4*>(&feat[i]) = v;
    }
    red[threadIdx.x] = kept;
    __syncthreads();
    for (int s = 128; s; s >>= 1) {
        if (threadIdx.x < s) red[threadIdx.x] += red[threadIdx.x + s];
        __syncthreads();
    }
    if (threadIdx.x == 0 && red[0]) atomicAdd(&scal[4], red[0]);
}

// ================= transpose W_dec [INDIM][DICT] -> Wt [DICT][INDIM] =================
__global__ void transpose_kernel(const float* __restrict__ W, float* __restrict__ Wt)
{
    __shared__ float t[32][33];
    const int x0 = blockIdx.x * 32;  // dict dim
    const int y0 = blockIdx.y * 32;  // input dim
    const int tx = threadIdx.x, ty = threadIdx.y;
    for (int r = ty; r < 32; r += 8)
        t[r][tx] = W[(size_t)(y0 + r) * DICT + x0 + tx];
    __syncthreads();
    for (int r = ty; r < 32; r += 8)
        Wt[(size_t)(x0 + r) * INDIM + y0 + tx] = t[tx][r];
}

// ================= sparse decode + loss (f64 loss accumulate) =================
template <bool TRANS>
__global__ __launch_bounds__(256) void decode_kernel(
    const float* __restrict__ feat, const float* __restrict__ Wmat,
    const float* __restrict__ b_dec, const float* __restrict__ x,
    float* __restrict__ recon, double* __restrict__ loss_sum)
{
    __shared__ float red[4][1024];
    __shared__ double redd[256];
    const int row = blockIdx.x;
    const int tid = threadIdx.x;
    const int w = tid >> 6;
    const int lane = tid & 63;
    float acc[16] = {};
    const float* frow = feat + (size_t)row * DICT;

    for (int ch = w; ch < DICT / 64; ch += 4) {
        const float v = frow[ch * 64 + lane];
        unsigned long long m = __ballot(v != 0.f);
        while (m) {
            const int bl = __ffsll((long long)m) - 1;
            m &= m - 1;
            const float fv = __shfl(v, bl);
            const int d = ch * 64 + bl;
            if (TRANS) {
                const float* wr = Wmat + (size_t)d * INDIM;
#pragma unroll
                for (int q = 0; q < 16; ++q) acc[q] += fv * wr[q * 64 + lane];
            } else {
#pragma unroll
                for (int q = 0; q < 16; ++q)
                    acc[q] += fv * Wmat[(size_t)(q * 64 + lane) * DICT + d];
            }
        }
    }
#pragma unroll
    for (int q = 0; q < 16; ++q) red[w][lane + 64 * q] = acc[q];
    __syncthreads();
    double lsum = 0.0;
    for (int i = tid; i < INDIM; i += 256) {
        const float s = red[0][i] + red[1][i] + red[2][i] + red[3][i] + b_dec[i];
        recon[(size_t)row * INDIM + i] = s;
        const double dlt = (double)s - (double)x[(size_t)row * INDIM + i];
        lsum += dlt * dlt;
    }
    redd[tid] = lsum;
    __syncthreads();
    for (int s = 128; s; s >>= 1) {
        if (tid < s) redd[tid] += redd[tid + s];
        __syncthreads();
    }
    if (tid == 0) atomicAdd(loss_sum, redd[0]);
}

// ================= finalize scalars =================
__global__ void finalize_kernel(const unsigned* __restrict__ scal, float* __restrict__ tail)
{
    const double* loss_d = reinterpret_cast<const double*>(&scal[12]);
    const float rec = (float)(loss_d[0] / (double)((size_t)BATCH * INDIM));
    tail[0] = rec;                            // loss
    tail[1] = rec;                            // reconstruction_loss
    tail[2] = 0.f;                            // sparsity_loss
    tail[3] = (float)scal[4] / (float)BATCH;  // l0
}

extern "C" void kernel_launch(void* const* d_in, const int* in_sizes, int n_in,
                              void* d_out, int out_size, void* d_ws, size_t ws_size,
                              hipStream_t stream)
{
    const float* x     = (const float*)d_in[0];
    const float* W_enc = (const float*)d_in[1];
    const float* b_enc = (const float*)d_in[2];
    const float* W_dec = (const float*)d_in[3];
    const float* b_dec = (const float*)d_in[4];

    float* recon = (float*)d_out;
    float* feat  = recon + (size_t)BATCH * INDIM;
    float* tail  = feat + NFEAT;

    unsigned* hist = (unsigned*)d_ws;
    unsigned* scal = (unsigned*)((char*)d_ws + SCAL_OFF);
    unsigned* cand = (unsigned*)((char*)d_ws + CAND_OFF);
    float*    Wt   = (float*)((char*)d_ws + WT_OFF);
    const bool big_ws = ws_size >= WT_OFF + (size_t)DICT * INDIM * sizeof(float);

    // zero hist + scalars (incl. f64 loss slot at scal[12..13])
    hipMemsetAsync(d_ws, 0, SCAL_OFF + 256, stream);

    encode_gemm<<<dim3(DICT / BN, BATCH / BM), 256, 0, stream>>>(x, W_enc, b_enc, b_dec, feat);
    hist_kernel<<<1024, 256, 0, stream>>>(feat, hist);
    findbin_kernel<<<1, 256, 0, stream>>>(hist, scal);
    collect_kernel<<<1024, 256, 0, stream>>>(feat, scal, cand);
    select_kernel<<<1, 256, 0, stream>>>(cand, scal);
    mask_kernel<<<2048, 256, 0, stream>>>(feat, scal);

    double* loss_sum = reinterpret_cast<double*>(&scal[12]);
    if (big_ws) {
        transpose_kernel<<<dim3(DICT / 32, INDIM / 32), dim3(32, 8), 0, stream>>>(W_dec, Wt);
        decode_kernel<true><<<BATCH, 256, 0, stream>>>(feat, Wt, b_dec, x, recon, loss_sum);
    } else {
        decode_kernel<false><<<BATCH, 256, 0, stream>>>(feat, W_dec, b_dec, x, recon, loss_sum);
    }
    finalize_kernel<<<1, 1, 0, stream>>>(scal, tail);
}

// Round 5
// 1736.400 us; speedup vs baseline: 1.8883x; 1.8883x over previous
//
#include <hip/hip_runtime.h>
#include <cstdint>
#include <cstddef>

#define BATCH   4096
#define INDIM   1024
#define DICT    16384
#define TOTK    (32 * 4096)
#define NFEAT   ((size_t)BATCH * DICT)   // 67108864
#define NBINS   8192
#define CAND_CAP (1u << 18)
#define C2_CAP   16384u
#define DELTA    3e-3f

// ---------------- ws layout (byte offsets) ----------------
// [0, 32K)    hist: 8192 x u32
// [32K]       scal: 64 x u32: 0=bin,1=above_bin,2=cand_cnt,3=thr_bits,
//             4=l0_count,6=ZL,7=ZH,8=above_zone,9=c2_cnt,12..13=loss(double)
// [64K..~1.1M) cand bit patterns
// [2M) c2idx u32[C2_CAP]   [3M) c2val f32[C2_CAP]   [4M) c2keep u32[C2_CAP]
// fast path: [8M) Ahi 8M  [16M) Alo 8M  [24M) Bhi 32M  [56M) Blo 32M  (end 88M)
//            Wt (64M) overlays [24M..88M) after encode.
// fallback:  Wt at [8M..72M)
#define SCAL_OFF 32768
#define CAND_OFF 65536
#define C2I_OFF  (2ull << 20)
#define C2V_OFF  (3ull << 20)
#define C2K_OFF  (4ull << 20)
#define AHI_OFF  (8ull << 20)
#define ALO_OFF  (16ull << 20)
#define BHI_OFF  (24ull << 20)
#define BLO_OFF  (56ull << 20)
#define WS_FAST_NEED (88ull << 20)
#define WT_FAST_OFF (24ull << 20)
#define WT_FB_OFF   (8ull << 20)

typedef __attribute__((ext_vector_type(8))) short short8;
typedef __attribute__((ext_vector_type(4))) float f32x4;

#define GL2LDS16(g, l) __builtin_amdgcn_global_load_lds( \
    (const __attribute__((address_space(1))) void*)(g), \
    (__attribute__((address_space(3))) void*)(l), 16, 0, 0)

// ======== split: Ahi/Alo = bf16-split(x - b_dec), Bhi/Blo = bf16-split(W_enc) ========
__device__ inline ushort bf16_rne(float a, float& back) {
    unsigned u = __float_as_uint(a);
    unsigned r = (u + 0x7FFFu + ((u >> 16) & 1u)) >> 16;
    back = __uint_as_float(r << 16);
    return (ushort)r;
}

__global__ __launch_bounds__(256) void split_kernel(
    const float* __restrict__ x, const float* __restrict__ W,
    const float* __restrict__ b_dec,
    ushort* __restrict__ Ahi, ushort* __restrict__ Alo,
    ushort* __restrict__ Bhi, ushort* __restrict__ Blo)
{
    const size_t NA = (size_t)BATCH * INDIM / 4;
    const size_t NB = (size_t)DICT * INDIM / 4;
    const size_t stride = (size_t)gridDim.x * blockDim.x;
    for (size_t i = (size_t)blockIdx.x * blockDim.x + threadIdx.x; i < NA + NB; i += stride) {
        float4 v;
        ushort* hp;
        ushort* lp;
        if (i < NA) {
            v = reinterpret_cast<const float4*>(x)[i];
            const float4 bd = reinterpret_cast<const float4*>(b_dec)[i & (INDIM / 4 - 1)];
            v.x -= bd.x; v.y -= bd.y; v.z -= bd.z; v.w -= bd.w;
            hp = Ahi + i * 4; lp = Alo + i * 4;
        } else {
            v = reinterpret_cast<const float4*>(W)[i - NA];
            hp = Bhi + (i - NA) * 4; lp = Blo + (i - NA) * 4;
        }
        ushort4 h, l;
        float back, lo;
        h.x = bf16_rne(v.x, back); lo = v.x - back; l.x = bf16_rne(lo, back);
        h.y = bf16_rne(v.y, back); lo = v.y - back; l.y = bf16_rne(lo, back);
        h.z = bf16_rne(v.z, back); lo = v.z - back; l.z = bf16_rne(lo, back);
        h.w = bf16_rne(v.w, back); lo = v.w - back; l.w = bf16_rne(lo, back);
        *reinterpret_cast<ushort4*>(hp) = h;
        *reinterpret_cast<ushort4*>(lp) = l;
    }
}

// ======== MFMA encode: feat = relu([Ahi|Ahi|Alo]·[Bhi;Blo;Bhi]^T + b_enc) ========
// 128x128 tile, BK=64, 4 waves 2x2, mfma_f32_16x16x32_bf16, LDS chunk^=(row&7) swizzle
__global__ __launch_bounds__(256) void encode_mfma(
    const ushort* __restrict__ Ahi, const ushort* __restrict__ Alo,
    const ushort* __restrict__ Bhi, const ushort* __restrict__ Blo,
    const float* __restrict__ b_enc, float* __restrict__ feat)
{
    __shared__ __align__(16) ushort As[128 * 64];
    __shared__ __align__(16) ushort Bs[128 * 64];
    const int tid = threadIdx.x;
    const int lane = tid & 63, wid = tid >> 6;
    // XCD-aware swizzle over 4096 blocks (4096 % 8 == 0 -> bijective)
    const int flat = blockIdx.y * gridDim.x + blockIdx.x;
    const int swz = (flat & 7) * 512 + (flat >> 3);
    const int n0 = (swz & 127) * 128;   // dict tile
    const int m0 = (swz >> 7) * 128;    // batch tile
    const int wm = wid >> 1, wn = wid & 1;

    f32x4 acc[4][4];
#pragma unroll
    for (int i = 0; i < 4; ++i)
#pragma unroll
        for (int j = 0; j < 4; ++j) acc[i][j] = (f32x4){0.f, 0.f, 0.f, 0.f};

    // staging: per inst i, rows i*32 + wid*8 + (lane>>3), swizzled src chunk
    const int srow = wid * 8 + (lane >> 3);
    const int schunk = (lane & 7) ^ (lane >> 3);
    const size_t abase = (size_t)(m0 + srow) * INDIM + schunk * 8;
    const size_t bbase = (size_t)(n0 + srow) * INDIM + schunk * 8;

    for (int t = 0; t < 48; ++t) {
        const int seg = t >> 4;
        const int koff = (t & 15) * 64;
        const ushort* Asrc = (seg < 2) ? Ahi : Alo;
        const ushort* Bsrc = (seg == 0) ? Bhi : ((seg == 1) ? Blo : Bhi);
#pragma unroll
        for (int i = 0; i < 4; ++i) {
            GL2LDS16(Asrc + abase + koff + (size_t)i * 32 * INDIM, &As[(i * 32 + wid * 8) * 64]);
            GL2LDS16(Bsrc + bbase + koff + (size_t)i * 32 * INDIM, &Bs[(i * 32 + wid * 8) * 64]);
        }
        __syncthreads();
#pragma unroll
        for (int kq2 = 0; kq2 < 2; ++kq2) {
            short8 af[4], bf[4];
#pragma unroll
            for (int f = 0; f < 4; ++f) {
                const int ra = wm * 64 + f * 16 + (lane & 15);
                const int ca = (kq2 * 4 + (lane >> 4)) ^ (ra & 7);
                af[f] = *reinterpret_cast<const short8*>(&As[ra * 64 + ca * 8]);
                const int rb = wn * 64 + f * 16 + (lane & 15);
                const int cb = (kq2 * 4 + (lane >> 4)) ^ (rb & 7);
                bf[f] = *reinterpret_cast<const short8*>(&Bs[rb * 64 + cb * 8]);
            }
#pragma unroll
            for (int fm = 0; fm < 4; ++fm)
#pragma unroll
                for (int fn = 0; fn < 4; ++fn)
                    acc[fm][fn] = __builtin_amdgcn_mfma_f32_16x16x32_bf16(
                        af[fm], bf[fn], acc[fm][fn], 0, 0, 0);
        }
        __syncthreads();
    }

    const int crow0 = m0 + wm * 64;
    const int ccol0 = n0 + wn * 64;
#pragma unroll
    for (int fm = 0; fm < 4; ++fm) {
#pragma unroll
        for (int fn = 0; fn < 4; ++fn) {
            const int col = ccol0 + fn * 16 + (lane & 15);
            const float be = b_enc[col];
#pragma unroll
            for (int r = 0; r < 4; ++r) {
                const int row = crow0 + fm * 16 + (lane >> 4) * 4 + r;
                feat[(size_t)row * DICT + col] = fmaxf(acc[fm][fn][r] + be, 0.f);
            }
        }
    }
}

// ======== fallback encode: exact OpenBLAS-mimic fp32 (round-4, passing) ========
#define BM 64
#define BN 64
#define BK 32
__global__ __launch_bounds__(256) void encode_gemm(
    const float* __restrict__ x, const float* __restrict__ W,
    const float* __restrict__ b_enc, const float* __restrict__ b_dec,
    float* __restrict__ feat)
{
    __shared__ __align__(16) float Asf[BK][BM];
    __shared__ __align__(16) float Wsf[BK][BN];
    const int tid = threadIdx.x;
    const int n0 = blockIdx.x * BN;
    const int m0 = blockIdx.y * BM;
    const int tm = tid >> 4, tn = tid & 15;
    const int sk = (tid & 7) * 4;
    const int sm = tid >> 3;

    float tot[4][4];
    const int kb[4] = {0, 384, 704, 1024};

    for (int p = 0; p < 3; ++p) {
        float acc[4][4] = {};
        for (int k0 = kb[p]; k0 < kb[p + 1]; k0 += BK) {
            const float4 bd = *reinterpret_cast<const float4*>(&b_dec[k0 + sk]);
#pragma unroll
            for (int r = 0; r < 2; ++r) {
                const int m = sm + r * 32;
                float4 v = *reinterpret_cast<const float4*>(&x[(size_t)(m0 + m) * INDIM + k0 + sk]);
                Asf[sk + 0][m] = v.x - bd.x;
                Asf[sk + 1][m] = v.y - bd.y;
                Asf[sk + 2][m] = v.z - bd.z;
                Asf[sk + 3][m] = v.w - bd.w;
                float4 w = *reinterpret_cast<const float4*>(&W[(size_t)(n0 + m) * INDIM + k0 + sk]);
                Wsf[sk + 0][m] = w.x;
                Wsf[sk + 1][m] = w.y;
                Wsf[sk + 2][m] = w.z;
                Wsf[sk + 3][m] = w.w;
            }
            __syncthreads();
#pragma unroll
            for (int kk = 0; kk < BK; ++kk) {
                const float4 av = *reinterpret_cast<const float4*>(&Asf[kk][tm * 4]);
                const float4 wv = *reinterpret_cast<const float4*>(&Wsf[kk][tn * 4]);
                const float a[4] = {av.x, av.y, av.z, av.w};
                const float b[4] = {wv.x, wv.y, wv.z, wv.w};
#pragma unroll
                for (int i = 0; i < 4; ++i)
#pragma unroll
                    for (int j = 0; j < 4; ++j)
                        acc[i][j] = fmaf(a[i], b[j], acc[i][j]);
            }
            __syncthreads();
        }
#pragma unroll
        for (int i = 0; i < 4; ++i)
#pragma unroll
            for (int j = 0; j < 4; ++j)
                tot[i][j] = (p == 0) ? acc[i][j] : (tot[i][j] + acc[i][j]);
    }

    const float4 be = *reinterpret_cast<const float4*>(&b_enc[n0 + tn * 4]);
    const float bea[4] = {be.x, be.y, be.z, be.w};
#pragma unroll
    for (int i = 0; i < 4; ++i) {
        const int row = m0 + tm * 4 + i;
        float4 out;
        out.x = fmaxf(tot[i][0] + bea[0], 0.0f);
        out.y = fmaxf(tot[i][1] + bea[1], 0.0f);
        out.z = fmaxf(tot[i][2] + bea[2], 0.0f);
        out.w = fmaxf(tot[i][3] + bea[3], 0.0f);
        *reinterpret_cast<float4*>(&feat[(size_t)row * DICT + n0 + tn * 4]) = out;
    }
}

// ================= histogram on top-14 bits of positive floats =================
__global__ __launch_bounds__(256) void hist_kernel(const float* __restrict__ feat,
                                                   unsigned* __restrict__ hist)
{
    __shared__ unsigned h[NBINS];
    for (int i = threadIdx.x; i < NBINS; i += blockDim.x) h[i] = 0;
    __syncthreads();
    const size_t stride = (size_t)gridDim.x * blockDim.x * 4;
    size_t base = ((size_t)blockIdx.x * blockDim.x + threadIdx.x) * 4;
    for (size_t i = base; i < NFEAT; i += stride) {
        const float4 v = *reinterpret_cast<const float4*>(&feat[i]);
        if (v.x > 0.f) atomicAdd(&h[__float_as_uint(v.x) >> 18], 1u);
        if (v.y > 0.f) atomicAdd(&h[__float_as_uint(v.y) >> 18], 1u);
        if (v.z > 0.f) atomicAdd(&h[__float_as_uint(v.z) >> 18], 1u);
        if (v.w > 0.f) atomicAdd(&h[__float_as_uint(v.w) >> 18], 1u);
    }
    __syncthreads();
    for (int i = threadIdx.x; i < NBINS; i += blockDim.x)
        if (h[i]) atomicAdd(&hist[i], h[i]);
}

// ================= find bin containing the TOTK-th largest =================
__global__ __launch_bounds__(256) void findbin_kernel(const unsigned* __restrict__ hist,
                                                      unsigned* __restrict__ scal)
{
    __shared__ unsigned tsum[256];
    __shared__ unsigned suffix[256];
    const int t = threadIdx.x;
    unsigned loc[32];
    unsigned s = 0;
#pragma unroll
    for (int i = 0; i < 32; ++i) { loc[i] = hist[t * 32 + i]; s += loc[i]; }
    tsum[t] = s;
    __syncthreads();
    if (t == 0) {
        unsigned run = 0;
        for (int i = 255; i >= 0; --i) { suffix[i] = run; run += tsum[i]; }
    }
    __syncthreads();
    unsigned cum = suffix[t];
    for (int i = 31; i >= 0; --i) {
        const unsigned nb = cum + loc[i];
        if (cum < TOTK && nb >= TOTK) {
            scal[0] = (unsigned)(t * 32 + i);
            scal[1] = cum;
        }
        cum = nb;
    }
}

// ============ collect candidate bit patterns in the crossing bin ============
__global__ __launch_bounds__(256) void collect_kernel(const float* __restrict__ feat,
                                                      unsigned* __restrict__ scal,
                                                      unsigned* __restrict__ cand)
{
    const unsigned b = scal[0];
    const size_t stride = (size_t)gridDim.x * blockDim.x;
    for (size_t i = (size_t)blockIdx.x * blockDim.x + threadIdx.x; i < NFEAT; i += stride) {
        const float v = feat[i];
        if (v > 0.f) {
            const unsigned u = __float_as_uint(v);
            if ((u >> 18) == b) {
                const unsigned idx = atomicAdd(&scal[2], 1u);
                if (idx < CAND_CAP) cand[idx] = u;
            }
        }
    }
}

// ====== exact rank-TOTK of stored values via binary search; zone bounds ======
__global__ __launch_bounds__(256) void select_kernel(const unsigned* __restrict__ cand,
                                                     unsigned* __restrict__ scal)
{
    __shared__ unsigned cnt[256];
    const unsigned b = scal[0];
    const unsigned above = scal[1];
    const unsigned C = min(scal[2], CAND_CAP);
    const unsigned j = TOTK - above;
    unsigned lo = b << 18;
    unsigned hi = ((b + 1) << 18) - 1;
    while (lo < hi) {
        const unsigned mid = lo + (hi - lo + 1) / 2;
        unsigned c = 0;
        for (unsigned i = threadIdx.x; i < C; i += 256) c += (cand[i] >= mid) ? 1u : 0u;
        cnt[threadIdx.x] = c;
        __syncthreads();
        for (int s = 128; s; s >>= 1) {
            if (threadIdx.x < s) cnt[threadIdx.x] += cnt[threadIdx.x + s];
            __syncthreads();
        }
        const unsigned tot = cnt[0];
        __syncthreads();
        if (tot >= j) lo = mid; else hi = mid - 1;
    }
    if (threadIdx.x == 0) {
        scal[3] = lo;
        const float tv = __uint_as_float(lo);
        scal[6] = __float_as_uint(fmaxf(tv - DELTA, 1e-30f));  // ZL
        scal[7] = __float_as_uint(tv + DELTA);                 // ZH
    }
}

// ====== fast path: count above-zone, gather in-zone candidate indices ======
__global__ __launch_bounds__(256) void collect2f_kernel(const float* __restrict__ feat,
                                                        unsigned* __restrict__ scal,
                                                        unsigned* __restrict__ c2idx)
{
    __shared__ unsigned red[256];
    const float ZLf = __uint_as_float(scal[6]);
    const float ZHf = __uint_as_float(scal[7]);
    unsigned above = 0;
    const size_t stride = (size_t)gridDim.x * blockDim.x * 4;
    size_t base = ((size_t)blockIdx.x * blockDim.x + threadIdx.x) * 4;
    for (size_t i = base; i < NFEAT; i += stride) {
        const float4 v = *reinterpret_cast<const float4*>(&feat[i]);
        const float a[4] = {v.x, v.y, v.z, v.w};
#pragma unroll
        for (int q = 0; q < 4; ++q) {
            if (a[q] > ZHf) above++;
            else if (a[q] >= ZLf) {
                const unsigned p = atomicAdd(&scal[9], 1u);
                if (p < C2_CAP) c2idx[p] = (unsigned)(i + q);
            }
        }
    }
    red[threadIdx.x] = above;
    __syncthreads();
    for (int s = 128; s; s >>= 1) {
        if (threadIdx.x < s) red[threadIdx.x] += red[threadIdx.x + s];
        __syncthreads();
    }
    if (threadIdx.x == 0 && red[0]) atomicAdd(&scal[8], red[0]);
}

// ====== recompute zone candidates with exact OpenBLAS-mimic fp32 ======
__global__ __launch_bounds__(256) void refine2_kernel(
    const float* __restrict__ x, const float* __restrict__ W,
    const float* __restrict__ b_enc, const float* __restrict__ b_dec,
    const unsigned* __restrict__ scal, const unsigned* __restrict__ c2idx,
    float* __restrict__ c2val)
{
    const unsigned n = min(scal[9], C2_CAP);
    const size_t stride = (size_t)gridDim.x * blockDim.x;
    for (unsigned c = blockIdx.x * blockDim.x + threadIdx.x; c < n; c += stride) {
        const unsigned i = c2idx[c];
        const int m = (int)(i >> 14);
        const int d = (int)(i & (DICT - 1));
        const float* xr = x + (size_t)m * INDIM;
        const float* wr = W + (size_t)d * INDIM;
        const int kb[4] = {0, 384, 704, 1024};
        float tot = 0.f;
        for (int p = 0; p < 3; ++p) {
            float a = 0.f;
#pragma unroll 8
            for (int k = kb[p]; k < kb[p + 1]; ++k)
                a = fmaf(xr[k] - b_dec[k], wr[k], a);
            tot = (p == 0) ? a : (tot + a);
        }
        c2val[c] = tot + b_enc[d];
    }
}

// ====== exact rank among candidates; top-j kept (ties kept, >= semantics) ======
__global__ __launch_bounds__(256) void rank2_kernel(const unsigned* __restrict__ scal,
                                                    const float* __restrict__ c2val,
                                                    unsigned* __restrict__ c2keep)
{
    const unsigned n = min(scal[9], C2_CAP);
    unsigned j = TOTK - scal[8];
    if (j > n) j = n;
    const size_t stride = (size_t)gridDim.x * blockDim.x;
    for (unsigned c = blockIdx.x * blockDim.x + threadIdx.x; c < n; c += stride) {
        const float v = c2val[c];
        unsigned g = 0;
        for (unsigned d = 0; d < n; ++d) g += (c2val[d] > v) ? 1u : 0u;
        c2keep[c] = (g < j) ? 1u : 0u;
    }
}

// ====== fast path: zero everything <= ZH (zone kept restored by fixup) ======
__global__ __launch_bounds__(256) void mask2_kernel(float* __restrict__ feat,
                                                    const unsigned* __restrict__ scal)
{
    const float ZHf = __uint_as_float(scal[7]);
    const size_t stride = (size_t)gridDim.x * blockDim.x * 4;
    size_t base = ((size_t)blockIdx.x * blockDim.x + threadIdx.x) * 4;
    for (size_t i = base; i < NFEAT; i += stride) {
        float4 v = *reinterpret_cast<float4*>(&feat[i]);
        bool any = false;
        if (v.x != 0.f && v.x <= ZHf) { v.x = 0.f; any = true; }
        if (v.y != 0.f && v.y <= ZHf) { v.y = 0.f; any = true; }
        if (v.z != 0.f && v.z <= ZHf) { v.z = 0.f; any = true; }
        if (v.w != 0.f && v.w <= ZHf) { v.w = 0.f; any = true; }
        if (any) *reinterpret_cast<float4*>(&feat[i]) = v;
    }
}

// ====== restore kept zone candidates with exact-mimic values; set l0 ======
__global__ __launch_bounds__(256) void fixup2_kernel(float* __restrict__ feat,
                                                     unsigned* __restrict__ scal,
                                                     const unsigned* __restrict__ c2idx,
                                                     const float* __restrict__ c2val,
                                                     const unsigned* __restrict__ c2keep)
{
    __shared__ unsigned red[256];
    const unsigned n = min(scal[9], C2_CAP);
    unsigned kept = 0;
    for (unsigned c = threadIdx.x; c < n; c += 256) {
        if (c2keep[c]) { feat[c2idx[c]] = c2val[c]; kept++; }
    }
    red[threadIdx.x] = kept;
    __syncthreads();
    for (int s = 128; s; s >>= 1) {
        if (threadIdx.x < s) red[threadIdx.x] += red[threadIdx.x + s];
        __syncthreads();
    }
    if (threadIdx.x == 0) scal[4] = scal[8] + red[0];
}

// ====== fallback: mask below exact threshold, count kept ======
__global__ __launch_bounds__(256) void mask_kernel(float* __restrict__ feat,
                                                   unsigned* __restrict__ scal)
{
    __shared__ unsigned red[256];
    const float thr = __uint_as_float(scal[3]);
    unsigned kept = 0;
    const size_t stride = (size_t)gridDim.x * blockDim.x * 4;
    size_t base = ((size_t)blockIdx.x * blockDim.x + threadIdx.x) * 4;
    for (size_t i = base; i < NFEAT; i += stride) {
        float4 v = *reinterpret_cast<float4*>(&feat[i]);
        bool any = false;
        if (v.x >= thr) kept++; else { if (v.x != 0.f) { v.x = 0.f; any = true; } }
        if (v.y >= thr) kept++; else { if (v.y != 0.f) { v.y = 0.f; any = true; } }
        if (v.z >= thr) kept++; else { if (v.z != 0.f) { v.z = 0.f; any = true; } }
        if (v.w >= thr) kept++; else { if (v.w != 0.f) { v.w = 0.f; any = true; } }
        if (any) *reinterpret_cast<float4*>(&feat[i]) = v;
    }
    red[threadIdx.x] = kept;
    __syncthreads();
    for (int s = 128; s; s >>= 1) {
        if (threadIdx.x < s) red[threadIdx.x] += red[threadIdx.x + s];
        __syncthreads();
    }
    if (threadIdx.x == 0 && red[0]) atomicAdd(&scal[4], red[0]);
}

// ============ transpose W_dec [INDIM][DICT] -> Wt [DICT][INDIM] ============
__global__ void transpose_kernel(const float* __restrict__ W, float* __restrict__ Wt)
{
    __shared__ float t[32][33];
    const int x0 = blockIdx.x * 32;
    const int y0 = blockIdx.y * 32;
    const int tx = threadIdx.x, ty = threadIdx.y;
    for (int r = ty; r < 32; r += 8)
        t[r][tx] = W[(size_t)(y0 + r) * DICT + x0 + tx];
    __syncthreads();
    for (int r = ty; r < 32; r += 8)
        Wt[(size_t)(x0 + r) * INDIM + y0 + tx] = t[tx][r];
}

// ================= sparse decode + loss (f64 loss accumulate) =================
template <bool TRANS>
__global__ __launch_bounds__(256) void decode_kernel(
    const float* __restrict__ feat, const float* __restrict__ Wmat,
    const float* __restrict__ b_dec, const float* __restrict__ x,
    float* __restrict__ recon, double* __restrict__ loss_sum)
{
    __shared__ float red[4][1024];
    __shared__ double redd[256];
    const int row = blockIdx.x;
    const int tid = threadIdx.x;
    const int w = tid >> 6;
    const int lane = tid & 63;
    float acc[16] = {};
    const float* frow = feat + (size_t)row * DICT;

    for (int ch = w; ch < DICT / 64; ch += 4) {
        const float v = frow[ch * 64 + lane];
        unsigned long long m = __ballot(v != 0.f);
        while (m) {
            const int bl = __ffsll((long long)m) - 1;
            m &= m - 1;
            const float fv = __shfl(v, bl);
            const int d = ch * 64 + bl;
            if (TRANS) {
                const float* wr = Wmat + (size_t)d * INDIM;
#pragma unroll
                for (int q = 0; q < 16; ++q) acc[q] += fv * wr[q * 64 + lane];
            } else {
#pragma unroll
                for (int q = 0; q < 16; ++q)
                    acc[q] += fv * Wmat[(size_t)(q * 64 + lane) * DICT + d];
            }
        }
    }
#pragma unroll
    for (int q = 0; q < 16; ++q) red[w][lane + 64 * q] = acc[q];
    __syncthreads();
    double lsum = 0.0;
    for (int i = tid; i < INDIM; i += 256) {
        const float s = red[0][i] + red[1][i] + red[2][i] + red[3][i] + b_dec[i];
        recon[(size_t)row * INDIM + i] = s;
        const double dlt = (double)s - (double)x[(size_t)row * INDIM + i];
        lsum += dlt * dlt;
    }
    redd[tid] = lsum;
    __syncthreads();
    for (int s = 128; s; s >>= 1) {
        if (tid < s) redd[tid] += redd[tid + s];
        __syncthreads();
    }
    if (tid == 0) atomicAdd(loss_sum, redd[0]);
}

// ================= finalize scalars =================
__global__ void finalize_kernel(const unsigned* __restrict__ scal, float* __restrict__ tail)
{
    const double* loss_d = reinterpret_cast<const double*>(&scal[12]);
    const float rec = (float)(loss_d[0] / (double)((size_t)BATCH * INDIM));
    tail[0] = rec;
    tail[1] = rec;
    tail[2] = 0.f;
    tail[3] = (float)scal[4] / (float)BATCH;
}

extern "C" void kernel_launch(void* const* d_in, const int* in_sizes, int n_in,
                              void* d_out, int out_size, void* d_ws, size_t ws_size,
                              hipStream_t stream)
{
    const float* x     = (const float*)d_in[0];
    const float* W_enc = (const float*)d_in[1];
    const float* b_enc = (const float*)d_in[2];
    const float* W_dec = (const float*)d_in[3];
    const float* b_dec = (const float*)d_in[4];

    float* recon = (float*)d_out;
    float* feat  = recon + (size_t)BATCH * INDIM;
    float* tail  = feat + NFEAT;

    unsigned* hist   = (unsigned*)d_ws;
    unsigned* scal   = (unsigned*)((char*)d_ws + SCAL_OFF);
    unsigned* cand   = (unsigned*)((char*)d_ws + CAND_OFF);
    unsigned* c2idx  = (unsigned*)((char*)d_ws + C2I_OFF);
    float*    c2val  = (float*)   ((char*)d_ws + C2V_OFF);
    unsigned* c2keep = (unsigned*)((char*)d_ws + C2K_OFF);

    const bool fast = ws_size >= WS_FAST_NEED;

    hipMemsetAsync(d_ws, 0, SCAL_OFF + 256, stream);
    double* loss_sum = reinterpret_cast<double*>(&scal[12]);

    if (fast) {
        ushort* Ahi = (ushort*)((char*)d_ws + AHI_OFF);
        ushort* Alo = (ushort*)((char*)d_ws + ALO_OFF);
        ushort* Bhi = (ushort*)((char*)d_ws + BHI_OFF);
        ushort* Blo = (ushort*)((char*)d_ws + BLO_OFF);
        float*  Wt  = (float*) ((char*)d_ws + WT_FAST_OFF);

        split_kernel<<<2048, 256, 0, stream>>>(x, W_enc, b_dec, Ahi, Alo, Bhi, Blo);
        encode_mfma<<<dim3(128, 32), 256, 0, stream>>>(Ahi, Alo, Bhi, Blo, b_enc, feat);
        hist_kernel<<<1024, 256, 0, stream>>>(feat, hist);
        findbin_kernel<<<1, 256, 0, stream>>>(hist, scal);
        collect_kernel<<<1024, 256, 0, stream>>>(feat, scal, cand);
        select_kernel<<<1, 256, 0, stream>>>(cand, scal);
        collect2f_kernel<<<1024, 256, 0, stream>>>(feat, scal, c2idx);
        refine2_kernel<<<64, 256, 0, stream>>>(x, W_enc, b_enc, b_dec, scal, c2idx, c2val);
        rank2_kernel<<<64, 256, 0, stream>>>(scal, c2val, c2keep);
        mask2_kernel<<<2048, 256, 0, stream>>>(feat, scal);
        fixup2_kernel<<<1, 256, 0, stream>>>(feat, scal, c2idx, c2val, c2keep);
        // Bhi/Blo no longer needed -> overlay Wt on their region
        transpose_kernel<<<dim3(DICT / 32, INDIM / 32), dim3(32, 8), 0, stream>>>(W_dec, Wt);
        decode_kernel<true><<<BATCH, 256, 0, stream>>>(feat, Wt, b_dec, x, recon, loss_sum);
    } else {
        encode_gemm<<<dim3(DICT / BN, BATCH / BM), 256, 0, stream>>>(x, W_enc, b_enc, b_dec, feat);
        hist_kernel<<<1024, 256, 0, stream>>>(feat, hist);
        findbin_kernel<<<1, 256, 0, stream>>>(hist, scal);
        collect_kernel<<<1024, 256, 0, stream>>>(feat, scal, cand);
        select_kernel<<<1, 256, 0, stream>>>(cand, scal);
        mask_kernel<<<2048, 256, 0, stream>>>(feat, scal);
        if (ws_size >= WT_FB_OFF + (size_t)DICT * INDIM * sizeof(float)) {
            float* Wt = (float*)((char*)d_ws + WT_FB_OFF);
            transpose_kernel<<<dim3(DICT / 32, INDIM / 32), dim3(32, 8), 0, stream>>>(W_dec, Wt);
            decode_kernel<true><<<BATCH, 256, 0, stream>>>(feat, Wt, b_dec, x, recon, loss_sum);
        } else {
            decode_kernel<false><<<BATCH, 256, 0, stream>>>(feat, W_dec, b_dec, x, recon, loss_sum);
        }
    }
    finalize_kernel<<<1, 1, 0, stream>>>(scal, tail);
}